// Round 9
// baseline (1720.864 us; speedup 1.0000x reference)
//
#include <hip/hip_runtime.h>
#include <hip/hip_bf16.h>

using f4 = float4;
typedef __attribute__((ext_vector_type(8))) short bf16x8;
typedef __attribute__((ext_vector_type(4))) float f32x4;

constexpr int IN_DIM = 512;
constexpr int DC     = 64;
constexpr int LCB    = 512;

__device__ __forceinline__ float wave_sum64(float v) {
#pragma unroll
    for (int m = 1; m < 64; m <<= 1) v += __shfl_xor(v, m, 64);
    return v;
}

__device__ __forceinline__ unsigned short f2bf(float v) {
    __hip_bfloat16 h = __float2bfloat16(v);
    return *(unsigned short*)&h;
}

// ---------------- codebook L2-normalize (also builds transposed copy) -------
__global__ void cbnorm_kernel(const float* __restrict__ cb, float* __restrict__ cbn,
                              float* __restrict__ cbnT, float* __restrict__ accv) {
    int row  = blockIdx.x * 4 + (threadIdx.x >> 6);  // 0..1535 (k*512 + l)
    int lane = threadIdx.x & 63;
    float v  = cb[(size_t)row * DC + lane];
    float ss = wave_sum64(v * v);
    float n  = sqrtf(ss);
    float o  = v / fmaxf(n, 1e-12f);
    cbn[(size_t)row * DC + lane] = o;
    int k = row >> 9, l = row & 511;
    cbnT[((size_t)k * DC + lane) * LCB + l] = o;
    if (blockIdx.x == 0 && threadIdx.x < 16) accv[threadIdx.x] = 0.f;
}

// ---------------- decoder weights -> transposed bf16 ------------------------
__global__ void wcvt_kernel(const float* __restrict__ D1, const float* __restrict__ D2,
                            const float* __restrict__ D3, unsigned short* __restrict__ D1t,
                            unsigned short* __restrict__ D2t, unsigned short* __restrict__ D3t) {
    int i = blockIdx.x * 256 + threadIdx.x;
    if (i < 128 * 64)  { int n = i >> 6, k = i & 63;  D1t[i] = f2bf(D1[(size_t)k * 128 + n]); }
    if (i < 256 * 128) { int n = i >> 7, k = i & 127; D2t[i] = f2bf(D2[(size_t)k * 256 + n]); }
    if (i < 512 * 256) { int n = i >> 8, k = i & 255; D3t[i] = f2bf(D3[(size_t)k * 512 + n]); }
}

// ---------------- avg_q (f32 q planes) -> bf16 ------------------------------
__global__ void avgq_kernel(const float* __restrict__ q3, unsigned short* __restrict__ Aq,
                            int n4, size_t planeStride) {
    int i = blockIdx.x * blockDim.x + threadIdx.x;
    if (i >= n4) return;
    f4 a = *(const f4*)&q3[(size_t)i * 4];
    f4 b = *(const f4*)&q3[planeStride + (size_t)i * 4];
    f4 c = *(const f4*)&q3[2 * planeStride + (size_t)i * 4];
    const float s = 1.f / 3.f;
    unsigned int lo = f2bf((a.x + b.x + c.x) * s) | ((unsigned int)f2bf((a.y + b.y + c.y) * s) << 16);
    unsigned int hi = f2bf((a.z + b.z + c.z) * s) | ((unsigned int)f2bf((a.w + b.w + c.w) * s) << 16);
    uint2 o; o.x = lo; o.y = hi;
    *(uint2*)&Aq[(size_t)i * 4] = o;
}

// ---------------- fp32 GEMM, BM=256 (16x8 per thread) -----------------------
// C = act(A @ W + bias). Doubles FMA per staged byte / per barrier vs 128-tile
// (56% -> target ~65-70% of fp32 peak). LDS 50.2KB -> 3 blocks/CU (12 waves,
// same as 128-tile's 12.8). Per-output FMA chain still p=0..Kin sequential ->
// bit-identical results (token anchor). blockIdx.z plane strides as before.
template <int RELU>
__global__ __launch_bounds__(256, 3)
void gemm_kernel(const float* __restrict__ A, const float* __restrict__ W,
                 const float* __restrict__ bias, float* __restrict__ C,
                 int Kin, int N,
                 size_t aK, size_t wK, size_t bK, size_t cK) {
    constexpr int BM = 256, BN = 128, BK = 32;
    __shared__ alignas(16) float As[BK][BM + 4];
    __shared__ alignas(16) float Ws[BK][BN + 4];
    const int z = blockIdx.z;
    A += (size_t)z * aK;  W += (size_t)z * wK;
    bias += (size_t)z * bK;  C += (size_t)z * cK;
    const int tid = threadIdx.x;
    const int tx = tid & 15, ty = tid >> 4;       // ty 0..15 -> 16 rows each
    const int row0 = blockIdx.x * BM, col0 = blockIdx.y * BN;

    float acc[16][8];
#pragma unroll
    for (int i = 0; i < 16; i++)
#pragma unroll
        for (int j = 0; j < 8; j++) acc[i][j] = 0.f;

    const int aRow = tid >> 3;         // 0..31
    const int aCol = (tid & 7) * 4;    // 0..28
    const int wRow = tid >> 5;         // 0..7
    const int wCol = (tid & 31) * 4;   // 0..124

    for (int kk = 0; kk < Kin; kk += BK) {
#pragma unroll
        for (int it = 0; it < 8; it++) {
            f4 v = *(const f4*)&A[(size_t)(row0 + aRow + it * 32) * Kin + kk + aCol];
            As[aCol + 0][aRow + it * 32] = v.x;
            As[aCol + 1][aRow + it * 32] = v.y;
            As[aCol + 2][aRow + it * 32] = v.z;
            As[aCol + 3][aRow + it * 32] = v.w;
        }
#pragma unroll
        for (int it = 0; it < 4; it++) {
            f4 v = *(const f4*)&W[(size_t)(kk + wRow + it * 8) * N + col0 + wCol];
            *(f4*)&Ws[wRow + it * 8][wCol] = v;
        }
        __syncthreads();
#pragma unroll
        for (int p = 0; p < BK; p++) {
            f4 a0 = *(const f4*)&As[p][ty * 16];
            f4 a1 = *(const f4*)&As[p][ty * 16 + 4];
            f4 a2 = *(const f4*)&As[p][ty * 16 + 8];
            f4 a3 = *(const f4*)&As[p][ty * 16 + 12];
            f4 w0 = *(const f4*)&Ws[p][tx * 8];
            f4 w1 = *(const f4*)&Ws[p][tx * 8 + 4];
            float av[16] = {a0.x, a0.y, a0.z, a0.w, a1.x, a1.y, a1.z, a1.w,
                            a2.x, a2.y, a2.z, a2.w, a3.x, a3.y, a3.z, a3.w};
            float wv[8] = {w0.x, w0.y, w0.z, w0.w, w1.x, w1.y, w1.z, w1.w};
#pragma unroll
            for (int i = 0; i < 16; i++)
#pragma unroll
                for (int j = 0; j < 8; j++)
                    acc[i][j] = fmaf(av[i], wv[j], acc[i][j]);
        }
        __syncthreads();
    }

#pragma unroll
    for (int i = 0; i < 16; i++) {
        const size_t r = (size_t)row0 + ty * 16 + i;
        float vrow[8];
#pragma unroll
        for (int j = 0; j < 8; j++) {
            float v = acc[i][j] + bias[col0 + tx * 8 + j];
            if (RELU) v = fmaxf(v, 0.f);
            vrow[j] = v;
        }
        *(f4*)&C[r * N + col0 + tx * 8]     = *(f4*)&vrow[0];
        *(f4*)&C[r * N + col0 + tx * 8 + 4] = *(f4*)&vrow[4];
    }
}

// ---------------- GEMM3 + LayerNorm epilogue: enc = LN(A@W3 + b3) -----------
__global__ __launch_bounds__(256, 4)
void gemm_ln_kernel(const float* __restrict__ A, const float* __restrict__ W,
                    const float* __restrict__ bias, const float* __restrict__ gamma,
                    const float* __restrict__ beta, float* __restrict__ enc, int Kin,
                    size_t aK, size_t wK, size_t bK, size_t eK) {
    constexpr int BM = 128, BK = 32;
    __shared__ alignas(16) float As[BK][BM + 4];
    __shared__ alignas(16) float Ws[BK][DC + 4];
    const int z = blockIdx.y;
    A += (size_t)z * aK;  W += (size_t)z * wK;
    bias += (size_t)z * bK;  enc += (size_t)z * eK;
    const int tid = threadIdx.x;
    const int tx = tid & 7, ty = tid >> 3;
    const int row0 = blockIdx.x * BM;

    float acc[4][8];
#pragma unroll
    for (int i = 0; i < 4; i++)
#pragma unroll
        for (int j = 0; j < 8; j++) acc[i][j] = 0.f;

    const int aRow = tid >> 3;
    const int aCol = (tid & 7) * 4;
    const int wRow = tid >> 4;
    const int wCol = (tid & 15) * 4;

    for (int kk = 0; kk < Kin; kk += BK) {
#pragma unroll
        for (int it = 0; it < 4; it++) {
            f4 v = *(const f4*)&A[(size_t)(row0 + aRow + it * 32) * Kin + kk + aCol];
            As[aCol + 0][aRow + it * 32] = v.x;
            As[aCol + 1][aRow + it * 32] = v.y;
            As[aCol + 2][aRow + it * 32] = v.z;
            As[aCol + 3][aRow + it * 32] = v.w;
        }
#pragma unroll
        for (int it = 0; it < 2; it++) {
            f4 v = *(const f4*)&W[(size_t)(kk + wRow + it * 16) * DC + wCol];
            *(f4*)&Ws[wRow + it * 16][wCol] = v;
        }
        __syncthreads();
#pragma unroll
        for (int p = 0; p < BK; p++) {
            f4 a  = *(const f4*)&As[p][ty * 4];
            f4 w0 = *(const f4*)&Ws[p][tx * 8];
            f4 w1 = *(const f4*)&Ws[p][tx * 8 + 4];
            float av[4] = {a.x, a.y, a.z, a.w};
            float wv[8] = {w0.x, w0.y, w0.z, w0.w, w1.x, w1.y, w1.z, w1.w};
#pragma unroll
            for (int i = 0; i < 4; i++)
#pragma unroll
                for (int j = 0; j < 8; j++)
                    acc[i][j] = fmaf(av[i], wv[j], acc[i][j]);
        }
        __syncthreads();
    }

#pragma unroll
    for (int i = 0; i < 4; i++) {
        float vrow[8];
#pragma unroll
        for (int j = 0; j < 8; j++) vrow[j] = acc[i][j] + bias[tx * 8 + j];
        float s = 0.f;
#pragma unroll
        for (int j = 0; j < 8; j++) s += vrow[j];
#pragma unroll
        for (int m = 1; m < 8; m <<= 1) s += __shfl_xor(s, m, 8);
        float mu = s * (1.f / 64.f);
        float d2 = 0.f;
#pragma unroll
        for (int j = 0; j < 8; j++) { float d = vrow[j] - mu; d2 = fmaf(d, d, d2); }
#pragma unroll
        for (int m = 1; m < 8; m <<= 1) d2 += __shfl_xor(d2, m, 8);
        float rs = 1.f / sqrtf(d2 * (1.f / 64.f) + 1e-5f);
#pragma unroll
        for (int j = 0; j < 8; j++) {
            int c = tx * 8 + j;
            vrow[j] = (vrow[j] - mu) * rs * gamma[c] + beta[c];
        }
        const size_t r = (size_t)row0 + ty * 4 + i;
        *(f4*)&enc[r * DC + tx * 8]     = *(f4*)&vrow[0];
        *(f4*)&enc[r * DC + tx * 8 + 4] = *(f4*)&vrow[4];
    }
}

// ---------------- quantize (f64 scores, round-6 proven) ---------------------
__global__ __launch_bounds__(256, 2)
void quant_kernel(float* __restrict__ enc, const float* __restrict__ cbT,
                  const float* __restrict__ cbn, float* __restrict__ out_tok,
                  float* __restrict__ sse_acc, int row_off_glob,
                  size_t eK, size_t cbTK, size_t cbnK) {
    constexpr int BM = 128;
    __shared__ alignas(16) float Es[DC][BM + 4];
    __shared__ alignas(16) float Cs[DC][64 + 4];
    __shared__ float red[4];
    const int k = blockIdx.y;
    enc += (size_t)k * eK;
    cbT += (size_t)k * cbTK;
    cbn += (size_t)k * cbnK;
    const int tid = threadIdx.x;
    const int tx = tid & 7, ty = tid >> 3;
    const int row0 = blockIdx.x * BM;

    {   // load enc tile transposed
        const int r  = tid >> 1;
        const int c0 = (tid & 1) * 32;
#pragma unroll
        for (int i = 0; i < 8; i++) {
            f4 v = *(const f4*)&enc[(size_t)(row0 + r) * DC + c0 + i * 4];
            Es[c0 + i * 4 + 0][r] = v.x;
            Es[c0 + i * 4 + 1][r] = v.y;
            Es[c0 + i * 4 + 2][r] = v.z;
            Es[c0 + i * 4 + 3][r] = v.w;
        }
    }

    double mx[4]; int mi[4];
#pragma unroll
    for (int i = 0; i < 4; i++) { mx[i] = -1.0e300; mi[i] = 0; }

    for (int lc = 0; lc < LCB; lc += 64) {
        __syncthreads();
        {
            const int p  = tid >> 2;
            const int c0 = (tid & 3) * 16;
#pragma unroll
            for (int i = 0; i < 4; i++)
                *(f4*)&Cs[p][c0 + i * 4] =
                    *(const f4*)&cbT[(size_t)p * LCB + lc + c0 + i * 4];
        }
        __syncthreads();
        double sc[4][8];
#pragma unroll
        for (int i = 0; i < 4; i++)
#pragma unroll
            for (int j = 0; j < 8; j++) sc[i][j] = 0.0;
#pragma unroll
        for (int p = 0; p < DC; p++) {
            f4 a  = *(const f4*)&Es[p][ty * 4];
            f4 w0 = *(const f4*)&Cs[p][tx * 8];
            f4 w1 = *(const f4*)&Cs[p][tx * 8 + 4];
            double av[4] = {a.x, a.y, a.z, a.w};
            double wv[8] = {w0.x, w0.y, w0.z, w0.w, w1.x, w1.y, w1.z, w1.w};
#pragma unroll
            for (int i = 0; i < 4; i++)
#pragma unroll
                for (int j = 0; j < 8; j++)
                    sc[i][j] = fma(av[i], wv[j], sc[i][j]);
        }
#pragma unroll
        for (int i = 0; i < 4; i++)
#pragma unroll
            for (int j = 0; j < 8; j++) {
                int l = lc + tx * 8 + j;
                if (sc[i][j] > mx[i]) { mx[i] = sc[i][j]; mi[i] = l; }
            }
    }

#pragma unroll
    for (int m = 1; m < 8; m <<= 1)
#pragma unroll
        for (int i = 0; i < 4; i++) {
            double omx = __shfl_xor(mx[i], m, 8);
            int    omi = __shfl_xor(mi[i], m, 8);
            if (omx > mx[i] || (omx == mx[i] && omi < mi[i])) { mx[i] = omx; mi[i] = omi; }
        }

    float sse = 0.f;
#pragma unroll
    for (int i = 0; i < 4; i++) {
        const int rl = ty * 4 + i;
        const size_t r = (size_t)row0 + rl;
        f4 q0 = *(const f4*)&cbn[(size_t)mi[i] * DC + tx * 8];
        f4 q1 = *(const f4*)&cbn[(size_t)mi[i] * DC + tx * 8 + 4];
        float qv[8] = {q0.x, q0.y, q0.z, q0.w, q1.x, q1.y, q1.z, q1.w};
#pragma unroll
        for (int j = 0; j < 8; j++) {
            float e = Es[tx * 8 + j][rl];
            float d = e - qv[j];
            sse = fmaf(d, d, sse);
        }
        *(f4*)&enc[r * DC + tx * 8]     = q0;
        *(f4*)&enc[r * DC + tx * 8 + 4] = q1;
        if (tx == 0) out_tok[(size_t)(row_off_glob + r) * 3 + k] = (float)mi[i];
    }
    sse = wave_sum64(sse);
    if ((tid & 63) == 0) red[tid >> 6] = sse;
    __syncthreads();
    if (tid == 0) atomicAdd(sse_acc, red[0] + red[1] + red[2] + red[3]);
}

// ---------------- bf16 MFMA GEMM for decoder (r7 proven) --------------------
template <int RELU, int FINAL>
__global__ __launch_bounds__(256, 2)
void mfma_dec_kernel(const unsigned short* __restrict__ A,
                     const unsigned short* __restrict__ Wt,
                     const float* __restrict__ bias,
                     unsigned short* __restrict__ Cb, float* __restrict__ Cf,
                     const float* __restrict__ x, float* __restrict__ sse_acc,
                     int Kin, int N) {
    constexpr int BM = 128, BN = 128, BK = 32;
    __shared__ alignas(16) unsigned short As[BM][BK + 8];
    __shared__ alignas(16) unsigned short Ws[BN][BK + 8];
    __shared__ float red[4];
    const int tid = threadIdx.x;
    const int l = tid & 63, wave = tid >> 6;
    const int wr = wave >> 1, wc = wave & 1;
    const int row0 = blockIdx.x * BM, col0 = blockIdx.y * BN;

    f32x4 acc[4][4];
#pragma unroll
    for (int m = 0; m < 4; m++)
#pragma unroll
        for (int n = 0; n < 4; n++) acc[m][n] = (f32x4){0.f, 0.f, 0.f, 0.f};

    const int sRow = tid >> 1;
    const int sCol = (tid & 1) * 16;

    for (int kt = 0; kt < Kin; kt += BK) {
        __syncthreads();
        {
            uint4 a0 = *(const uint4*)&A[(size_t)(row0 + sRow) * Kin + kt + sCol];
            uint4 a1 = *(const uint4*)&A[(size_t)(row0 + sRow) * Kin + kt + sCol + 8];
            uint4 w0 = *(const uint4*)&Wt[(size_t)(col0 + sRow) * Kin + kt + sCol];
            uint4 w1 = *(const uint4*)&Wt[(size_t)(col0 + sRow) * Kin + kt + sCol + 8];
            *(uint4*)&As[sRow][sCol]     = a0;
            *(uint4*)&As[sRow][sCol + 8] = a1;
            *(uint4*)&Ws[sRow][sCol]     = w0;
            *(uint4*)&Ws[sRow][sCol + 8] = w1;
        }
        __syncthreads();
        bf16x8 af[4], bf[4];
        const int k0 = (l >> 4) * 8;
        const int lr = l & 15;
#pragma unroll
        for (int m = 0; m < 4; m++)
            af[m] = *(const bf16x8*)&As[wr * 64 + m * 16 + lr][k0];
#pragma unroll
        for (int n = 0; n < 4; n++)
            bf[n] = *(const bf16x8*)&Ws[wc * 64 + n * 16 + lr][k0];
#pragma unroll
        for (int m = 0; m < 4; m++)
#pragma unroll
            for (int n = 0; n < 4; n++)
                acc[m][n] = __builtin_amdgcn_mfma_f32_16x16x32_bf16(af[m], bf[n], acc[m][n], 0, 0, 0);
    }

    float sse = 0.f;
#pragma unroll
    for (int m = 0; m < 4; m++)
#pragma unroll
        for (int n = 0; n < 4; n++) {
            const int rbase = row0 + wr * 64 + m * 16 + (l >> 4) * 4;
            const int c = col0 + wc * 64 + n * 16 + (l & 15);
            const float b = bias[c];
#pragma unroll
            for (int rr = 0; rr < 4; rr++) {
                float v = acc[m][n][rr] + b;
                if (FINAL) {
                    float d = v - x[(size_t)(rbase + rr) * N + c];
                    sse = fmaf(d, d, sse);
                    Cf[(size_t)(rbase + rr) * N + c] = v;
                } else {
                    if (RELU) v = fmaxf(v, 0.f);
                    Cb[(size_t)(rbase + rr) * N + c] = f2bf(v);
                }
            }
        }
    if (FINAL) {
        sse = wave_sum64(sse);
        if ((tid & 63) == 0) red[tid >> 6] = sse;
        __syncthreads();
        if (tid == 0) atomicAdd(sse_acc, red[0] + red[1] + red[2] + red[3]);
    }
}

// ---------------- finalize scalars ----------------
__global__ void finalize_kernel(const float* __restrict__ accv,
                                float* __restrict__ outs,
                                float inv_rec, float inv_cb) {
    if (threadIdx.x == 0) {
        outs[0] = accv[1] * inv_rec;     // recon_loss
        float cbl = accv[0] * inv_cb;
        outs[1] = cbl;                   // codebook_loss
        outs[2] = cbl;                   // commitment_loss (forward-equal)
    }
}

extern "C" void kernel_launch(void* const* d_in, const int* in_sizes, int n_in,
                              void* d_out, int out_size, void* d_ws, size_t ws_size,
                              hipStream_t stream) {
    const float* x     = (const float*)d_in[0];
    const float* W1    = (const float*)d_in[1];
    const float* b1    = (const float*)d_in[2];
    const float* W2    = (const float*)d_in[3];
    const float* b2    = (const float*)d_in[4];
    const float* W3    = (const float*)d_in[5];
    const float* b3    = (const float*)d_in[6];
    const float* gamma = (const float*)d_in[7];
    const float* beta  = (const float*)d_in[8];
    const float* cb    = (const float*)d_in[9];
    const float* D1    = (const float*)d_in[10];
    const float* c1    = (const float*)d_in[11];
    const float* D2    = (const float*)d_in[12];
    const float* c2    = (const float*)d_in[13];
    const float* D3    = (const float*)d_in[14];
    const float* c3    = (const float*)d_in[15];
    const int M = in_sizes[0] / IN_DIM;   // 65536

    float* out     = (float*)d_out;
    float* out_tok = out;                          // M*3
    float* out_rec = out + (size_t)M * 3;          // M*512
    float* out_sc  = out_rec + (size_t)M * IN_DIM; // 3 scalars

    const size_t fixedB  = (size_t)(16 + 2 * 3 * LCB * DC) * 4 + (size_t)172032 * 2;
    const size_t perRowB = (size_t)(3 * DC + 3 * 256 + 3 * 128) * 4;   // 5376
    int C = 4096;
    for (int cand = 65536; cand >= 4096; cand >>= 1)
        if (fixedB + (size_t)cand * perRowB <= ws_size) { C = cand; break; }

    float* ws    = (float*)d_ws;
    float* accv  = ws;                                     // 16
    float* cbn   = accv + 16;                              // 3*512*64
    float* cbnT  = cbn + 3 * LCB * DC;                     // 3*64*512
    unsigned short* D1t = (unsigned short*)(cbnT + 3 * DC * LCB);  // 128*64
    unsigned short* D2t = D1t + 128 * 64;                  // 256*128
    unsigned short* D3t = D2t + 256 * 128;                 // 512*256
    float* enc3  = (float*)(D3t + 512 * 256);              // 3*C*64 (enc, then q)
    float* H1    = enc3 + (size_t)3 * C * DC;              // 3*C*256
    float* H2    = H1 + (size_t)3 * C * 256;               // 3*C*128
    unsigned short* Aq  = (unsigned short*)H2;             // C*64 (aliases dead H2)
    unsigned short* H1b = Aq + (size_t)C * 64;             // C*128
    unsigned short* H2b = H1b + (size_t)C * 128;           // C*256

    cbnorm_kernel<<<dim3(3 * LCB / 4), dim3(256), 0, stream>>>(cb, cbn, cbnT, accv);
    wcvt_kernel<<<dim3(512), dim3(256), 0, stream>>>(D1, D2, D3, D1t, D2t, D3t);

    for (int off = 0; off < M; off += C) {
        const float* xc  = x + (size_t)off * IN_DIM;
        float*       rcc = out_rec + (size_t)off * IN_DIM;

        gemm_kernel<1><<<dim3(C / 256, 2, 3), dim3(256), 0, stream>>>(
            xc, W1, b1, H1, 512, 256,
            0, (size_t)512 * 256, 256, (size_t)C * 256);
        gemm_kernel<1><<<dim3(C / 256, 1, 3), dim3(256), 0, stream>>>(
            H1, W2, b2, H2, 256, 128,
            (size_t)C * 256, (size_t)256 * 128, 128, (size_t)C * 128);
        gemm_ln_kernel<<<dim3(C / 128, 3), dim3(256), 0, stream>>>(
            H2, W3, b3, gamma, beta, enc3, 128,
            (size_t)C * 128, (size_t)128 * 64, 64, (size_t)C * DC);
        quant_kernel<<<dim3(C / 128, 3), dim3(256), 0, stream>>>(
            enc3, cbnT, cbn, out_tok, accv + 0, off,
            (size_t)C * DC, (size_t)DC * LCB, (size_t)LCB * DC);

        avgq_kernel<<<dim3((C * 16 + 255) / 256), dim3(256), 0, stream>>>(
            enc3, Aq, C * 16, (size_t)C * DC);
        mfma_dec_kernel<1, 0><<<dim3(C / 128, 1), dim3(256), 0, stream>>>(
            Aq, D1t, c1, H1b, nullptr, nullptr, nullptr, 64, 128);
        mfma_dec_kernel<1, 0><<<dim3(C / 128, 2), dim3(256), 0, stream>>>(
            H1b, D2t, c2, H2b, nullptr, nullptr, nullptr, 128, 256);
        mfma_dec_kernel<0, 1><<<dim3(C / 128, 4), dim3(256), 0, stream>>>(
            H2b, D3t, c3, nullptr, rcc, xc, accv + 1, 256, 512);
    }

    finalize_kernel<<<dim3(1), dim3(64), 0, stream>>>(
        accv, out_sc, 1.f / ((float)M * IN_DIM), 1.f / ((float)M * DC));
}

// Round 10
// 1306.916 us; speedup vs baseline: 1.3167x; 1.3167x over previous
//
#include <hip/hip_runtime.h>
#include <hip/hip_bf16.h>

using f4 = float4;
typedef __attribute__((ext_vector_type(8))) short bf16x8;
typedef __attribute__((ext_vector_type(4))) float f32x4;

constexpr int IN_DIM = 512;
constexpr int DC     = 64;
constexpr int LCB    = 512;

__device__ __forceinline__ float wave_sum64(float v) {
#pragma unroll
    for (int m = 1; m < 64; m <<= 1) v += __shfl_xor(v, m, 64);
    return v;
}

__device__ __forceinline__ unsigned short f2bf(float v) {
    __hip_bfloat16 h = __float2bfloat16(v);
    return *(unsigned short*)&h;
}

// ---------------- codebook L2-normalize (also builds transposed copy) -------
__global__ void cbnorm_kernel(const float* __restrict__ cb, float* __restrict__ cbn,
                              float* __restrict__ cbnT, float* __restrict__ accv) {
    int row  = blockIdx.x * 4 + (threadIdx.x >> 6);  // 0..1535 (k*512 + l)
    int lane = threadIdx.x & 63;
    float v  = cb[(size_t)row * DC + lane];
    float ss = wave_sum64(v * v);
    float n  = sqrtf(ss);
    float o  = v / fmaxf(n, 1e-12f);
    cbn[(size_t)row * DC + lane] = o;
    int k = row >> 9, l = row & 511;
    cbnT[((size_t)k * DC + lane) * LCB + l] = o;
    if (blockIdx.x == 0 && threadIdx.x < 16) accv[threadIdx.x] = 0.f;
}

// ---------------- decoder weights -> transposed bf16 ------------------------
__global__ void wcvt_kernel(const float* __restrict__ D1, const float* __restrict__ D2,
                            const float* __restrict__ D3, unsigned short* __restrict__ D1t,
                            unsigned short* __restrict__ D2t, unsigned short* __restrict__ D3t) {
    int i = blockIdx.x * 256 + threadIdx.x;
    if (i < 128 * 64)  { int n = i >> 6, k = i & 63;  D1t[i] = f2bf(D1[(size_t)k * 128 + n]); }
    if (i < 256 * 128) { int n = i >> 7, k = i & 127; D2t[i] = f2bf(D2[(size_t)k * 256 + n]); }
    if (i < 512 * 256) { int n = i >> 8, k = i & 255; D3t[i] = f2bf(D3[(size_t)k * 512 + n]); }
}

// ---------------- avg_q (f32 q planes) -> bf16 ------------------------------
__global__ void avgq_kernel(const float* __restrict__ q3, unsigned short* __restrict__ Aq,
                            int n4, size_t planeStride) {
    int i = blockIdx.x * blockDim.x + threadIdx.x;
    if (i >= n4) return;
    f4 a = *(const f4*)&q3[(size_t)i * 4];
    f4 b = *(const f4*)&q3[planeStride + (size_t)i * 4];
    f4 c = *(const f4*)&q3[2 * planeStride + (size_t)i * 4];
    const float s = 1.f / 3.f;
    unsigned int lo = f2bf((a.x + b.x + c.x) * s) | ((unsigned int)f2bf((a.y + b.y + c.y) * s) << 16);
    unsigned int hi = f2bf((a.z + b.z + c.z) * s) | ((unsigned int)f2bf((a.w + b.w + c.w) * s) << 16);
    uint2 o; o.x = lo; o.y = hi;
    *(uint2*)&Aq[(size_t)i * 4] = o;
}

// ---------------- fp32 GEMM, BM=256 x BN=128, 512 threads, 8x8/thread -------
// Same per-thread shape/FMA order as the proven r8 kernel (64 acc regs, no
// spill; bit-identical outputs -> token anchor). Vs r8: W-tile reuse x2,
// 2x FMA per barrier, fewer staged bytes/FLOP. LDS 50KB -> 2 blocks/CU
// (16 waves/CU, same as r8). blockIdx.z plane strides as before.
template <int RELU>
__global__ __launch_bounds__(512, 2)
void gemm_kernel(const float* __restrict__ A, const float* __restrict__ W,
                 const float* __restrict__ bias, float* __restrict__ C,
                 int Kin, int N,
                 size_t aK, size_t wK, size_t bK, size_t cK) {
    constexpr int BM = 256, BN = 128, BK = 32;
    __shared__ alignas(16) float As[BK][BM + 4];
    __shared__ alignas(16) float Ws[BK][BN + 4];
    const int z = blockIdx.z;
    A += (size_t)z * aK;  W += (size_t)z * wK;
    bias += (size_t)z * bK;  C += (size_t)z * cK;
    const int tid = threadIdx.x;
    const int tx = tid & 15, ty = tid >> 4;       // ty 0..31 rows-of-8, tx 0..15 cols-of-8
    const int row0 = blockIdx.x * BM, col0 = blockIdx.y * BN;

    float acc[8][8];
#pragma unroll
    for (int i = 0; i < 8; i++)
#pragma unroll
        for (int j = 0; j < 8; j++) acc[i][j] = 0.f;

    const int aRow = tid >> 3;         // 0..63
    const int aCol = (tid & 7) * 4;    // 0..28
    const int wRow = tid >> 5;         // 0..15
    const int wCol = (tid & 31) * 4;   // 0..124

    for (int kk = 0; kk < Kin; kk += BK) {
#pragma unroll
        for (int it = 0; it < 4; it++) {
            f4 v = *(const f4*)&A[(size_t)(row0 + aRow + it * 64) * Kin + kk + aCol];
            As[aCol + 0][aRow + it * 64] = v.x;
            As[aCol + 1][aRow + it * 64] = v.y;
            As[aCol + 2][aRow + it * 64] = v.z;
            As[aCol + 3][aRow + it * 64] = v.w;
        }
#pragma unroll
        for (int it = 0; it < 2; it++) {
            f4 v = *(const f4*)&W[(size_t)(kk + wRow + it * 16) * N + col0 + wCol];
            *(f4*)&Ws[wRow + it * 16][wCol] = v;
        }
        __syncthreads();
#pragma unroll
        for (int p = 0; p < BK; p++) {
            f4 a0 = *(const f4*)&As[p][ty * 8];
            f4 a1 = *(const f4*)&As[p][ty * 8 + 4];
            f4 w0 = *(const f4*)&Ws[p][tx * 8];
            f4 w1 = *(const f4*)&Ws[p][tx * 8 + 4];
            float av[8] = {a0.x, a0.y, a0.z, a0.w, a1.x, a1.y, a1.z, a1.w};
            float wv[8] = {w0.x, w0.y, w0.z, w0.w, w1.x, w1.y, w1.z, w1.w};
#pragma unroll
            for (int i = 0; i < 8; i++)
#pragma unroll
                for (int j = 0; j < 8; j++)
                    acc[i][j] = fmaf(av[i], wv[j], acc[i][j]);
        }
        __syncthreads();
    }

#pragma unroll
    for (int i = 0; i < 8; i++) {
        const size_t r = (size_t)row0 + ty * 8 + i;
        float vrow[8];
#pragma unroll
        for (int j = 0; j < 8; j++) {
            float v = acc[i][j] + bias[col0 + tx * 8 + j];
            if (RELU) v = fmaxf(v, 0.f);
            vrow[j] = v;
        }
        *(f4*)&C[r * N + col0 + tx * 8]     = *(f4*)&vrow[0];
        *(f4*)&C[r * N + col0 + tx * 8 + 4] = *(f4*)&vrow[4];
    }
}

// ---------------- GEMM3 + LayerNorm epilogue: enc = LN(A@W3 + b3) -----------
__global__ __launch_bounds__(256, 4)
void gemm_ln_kernel(const float* __restrict__ A, const float* __restrict__ W,
                    const float* __restrict__ bias, const float* __restrict__ gamma,
                    const float* __restrict__ beta, float* __restrict__ enc, int Kin,
                    size_t aK, size_t wK, size_t bK, size_t eK) {
    constexpr int BM = 128, BK = 32;
    __shared__ alignas(16) float As[BK][BM + 4];
    __shared__ alignas(16) float Ws[BK][DC + 4];
    const int z = blockIdx.y;
    A += (size_t)z * aK;  W += (size_t)z * wK;
    bias += (size_t)z * bK;  enc += (size_t)z * eK;
    const int tid = threadIdx.x;
    const int tx = tid & 7, ty = tid >> 3;
    const int row0 = blockIdx.x * BM;

    float acc[4][8];
#pragma unroll
    for (int i = 0; i < 4; i++)
#pragma unroll
        for (int j = 0; j < 8; j++) acc[i][j] = 0.f;

    const int aRow = tid >> 3;
    const int aCol = (tid & 7) * 4;
    const int wRow = tid >> 4;
    const int wCol = (tid & 15) * 4;

    for (int kk = 0; kk < Kin; kk += BK) {
#pragma unroll
        for (int it = 0; it < 4; it++) {
            f4 v = *(const f4*)&A[(size_t)(row0 + aRow + it * 32) * Kin + kk + aCol];
            As[aCol + 0][aRow + it * 32] = v.x;
            As[aCol + 1][aRow + it * 32] = v.y;
            As[aCol + 2][aRow + it * 32] = v.z;
            As[aCol + 3][aRow + it * 32] = v.w;
        }
#pragma unroll
        for (int it = 0; it < 2; it++) {
            f4 v = *(const f4*)&W[(size_t)(kk + wRow + it * 16) * DC + wCol];
            *(f4*)&Ws[wRow + it * 16][wCol] = v;
        }
        __syncthreads();
#pragma unroll
        for (int p = 0; p < BK; p++) {
            f4 a  = *(const f4*)&As[p][ty * 4];
            f4 w0 = *(const f4*)&Ws[p][tx * 8];
            f4 w1 = *(const f4*)&Ws[p][tx * 8 + 4];
            float av[4] = {a.x, a.y, a.z, a.w};
            float wv[8] = {w0.x, w0.y, w0.z, w0.w, w1.x, w1.y, w1.z, w1.w};
#pragma unroll
            for (int i = 0; i < 4; i++)
#pragma unroll
                for (int j = 0; j < 8; j++)
                    acc[i][j] = fmaf(av[i], wv[j], acc[i][j]);
        }
        __syncthreads();
    }

#pragma unroll
    for (int i = 0; i < 4; i++) {
        float vrow[8];
#pragma unroll
        for (int j = 0; j < 8; j++) vrow[j] = acc[i][j] + bias[tx * 8 + j];
        float s = 0.f;
#pragma unroll
        for (int j = 0; j < 8; j++) s += vrow[j];
#pragma unroll
        for (int m = 1; m < 8; m <<= 1) s += __shfl_xor(s, m, 8);
        float mu = s * (1.f / 64.f);
        float d2 = 0.f;
#pragma unroll
        for (int j = 0; j < 8; j++) { float d = vrow[j] - mu; d2 = fmaf(d, d, d2); }
#pragma unroll
        for (int m = 1; m < 8; m <<= 1) d2 += __shfl_xor(d2, m, 8);
        float rs = 1.f / sqrtf(d2 * (1.f / 64.f) + 1e-5f);
#pragma unroll
        for (int j = 0; j < 8; j++) {
            int c = tx * 8 + j;
            vrow[j] = (vrow[j] - mu) * rs * gamma[c] + beta[c];
        }
        const size_t r = (size_t)row0 + ty * 4 + i;
        *(f4*)&enc[r * DC + tx * 8]     = *(f4*)&vrow[0];
        *(f4*)&enc[r * DC + tx * 8 + 4] = *(f4*)&vrow[4];
    }
}

// ---------------- quantize (f64 scores, round-6 proven) ---------------------
__global__ __launch_bounds__(256, 2)
void quant_kernel(float* __restrict__ enc, const float* __restrict__ cbT,
                  const float* __restrict__ cbn, float* __restrict__ out_tok,
                  float* __restrict__ sse_acc, int row_off_glob,
                  size_t eK, size_t cbTK, size_t cbnK) {
    constexpr int BM = 128;
    __shared__ alignas(16) float Es[DC][BM + 4];
    __shared__ alignas(16) float Cs[DC][64 + 4];
    __shared__ float red[4];
    const int k = blockIdx.y;
    enc += (size_t)k * eK;
    cbT += (size_t)k * cbTK;
    cbn += (size_t)k * cbnK;
    const int tid = threadIdx.x;
    const int tx = tid & 7, ty = tid >> 3;
    const int row0 = blockIdx.x * BM;

    {   // load enc tile transposed
        const int r  = tid >> 1;
        const int c0 = (tid & 1) * 32;
#pragma unroll
        for (int i = 0; i < 8; i++) {
            f4 v = *(const f4*)&enc[(size_t)(row0 + r) * DC + c0 + i * 4];
            Es[c0 + i * 4 + 0][r] = v.x;
            Es[c0 + i * 4 + 1][r] = v.y;
            Es[c0 + i * 4 + 2][r] = v.z;
            Es[c0 + i * 4 + 3][r] = v.w;
        }
    }

    double mx[4]; int mi[4];
#pragma unroll
    for (int i = 0; i < 4; i++) { mx[i] = -1.0e300; mi[i] = 0; }

    for (int lc = 0; lc < LCB; lc += 64) {
        __syncthreads();
        {
            const int p  = tid >> 2;
            const int c0 = (tid & 3) * 16;
#pragma unroll
            for (int i = 0; i < 4; i++)
                *(f4*)&Cs[p][c0 + i * 4] =
                    *(const f4*)&cbT[(size_t)p * LCB + lc + c0 + i * 4];
        }
        __syncthreads();
        double sc[4][8];
#pragma unroll
        for (int i = 0; i < 4; i++)
#pragma unroll
            for (int j = 0; j < 8; j++) sc[i][j] = 0.0;
#pragma unroll
        for (int p = 0; p < DC; p++) {
            f4 a  = *(const f4*)&Es[p][ty * 4];
            f4 w0 = *(const f4*)&Cs[p][tx * 8];
            f4 w1 = *(const f4*)&Cs[p][tx * 8 + 4];
            double av[4] = {a.x, a.y, a.z, a.w};
            double wv[8] = {w0.x, w0.y, w0.z, w0.w, w1.x, w1.y, w1.z, w1.w};
#pragma unroll
            for (int i = 0; i < 4; i++)
#pragma unroll
                for (int j = 0; j < 8; j++)
                    sc[i][j] = fma(av[i], wv[j], sc[i][j]);
        }
#pragma unroll
        for (int i = 0; i < 4; i++)
#pragma unroll
            for (int j = 0; j < 8; j++) {
                int l = lc + tx * 8 + j;
                if (sc[i][j] > mx[i]) { mx[i] = sc[i][j]; mi[i] = l; }
            }
    }

#pragma unroll
    for (int m = 1; m < 8; m <<= 1)
#pragma unroll
        for (int i = 0; i < 4; i++) {
            double omx = __shfl_xor(mx[i], m, 8);
            int    omi = __shfl_xor(mi[i], m, 8);
            if (omx > mx[i] || (omx == mx[i] && omi < mi[i])) { mx[i] = omx; mi[i] = omi; }
        }

    float sse = 0.f;
#pragma unroll
    for (int i = 0; i < 4; i++) {
        const int rl = ty * 4 + i;
        const size_t r = (size_t)row0 + rl;
        f4 q0 = *(const f4*)&cbn[(size_t)mi[i] * DC + tx * 8];
        f4 q1 = *(const f4*)&cbn[(size_t)mi[i] * DC + tx * 8 + 4];
        float qv[8] = {q0.x, q0.y, q0.z, q0.w, q1.x, q1.y, q1.z, q1.w};
#pragma unroll
        for (int j = 0; j < 8; j++) {
            float e = Es[tx * 8 + j][rl];
            float d = e - qv[j];
            sse = fmaf(d, d, sse);
        }
        *(f4*)&enc[r * DC + tx * 8]     = q0;
        *(f4*)&enc[r * DC + tx * 8 + 4] = q1;
        if (tx == 0) out_tok[(size_t)(row_off_glob + r) * 3 + k] = (float)mi[i];
    }
    sse = wave_sum64(sse);
    if ((tid & 63) == 0) red[tid >> 6] = sse;
    __syncthreads();
    if (tid == 0) atomicAdd(sse_acc, red[0] + red[1] + red[2] + red[3]);
}

// ---------------- bf16 MFMA GEMM for decoder (r7 proven) --------------------
template <int RELU, int FINAL>
__global__ __launch_bounds__(256, 2)
void mfma_dec_kernel(const unsigned short* __restrict__ A,
                     const unsigned short* __restrict__ Wt,
                     const float* __restrict__ bias,
                     unsigned short* __restrict__ Cb, float* __restrict__ Cf,
                     const float* __restrict__ x, float* __restrict__ sse_acc,
                     int Kin, int N) {
    constexpr int BM = 128, BN = 128, BK = 32;
    __shared__ alignas(16) unsigned short As[BM][BK + 8];
    __shared__ alignas(16) unsigned short Ws[BN][BK + 8];
    __shared__ float red[4];
    const int tid = threadIdx.x;
    const int l = tid & 63, wave = tid >> 6;
    const int wr = wave >> 1, wc = wave & 1;
    const int row0 = blockIdx.x * BM, col0 = blockIdx.y * BN;

    f32x4 acc[4][4];
#pragma unroll
    for (int m = 0; m < 4; m++)
#pragma unroll
        for (int n = 0; n < 4; n++) acc[m][n] = (f32x4){0.f, 0.f, 0.f, 0.f};

    const int sRow = tid >> 1;
    const int sCol = (tid & 1) * 16;

    for (int kt = 0; kt < Kin; kt += BK) {
        __syncthreads();
        {
            uint4 a0 = *(const uint4*)&A[(size_t)(row0 + sRow) * Kin + kt + sCol];
            uint4 a1 = *(const uint4*)&A[(size_t)(row0 + sRow) * Kin + kt + sCol + 8];
            uint4 w0 = *(const uint4*)&Wt[(size_t)(col0 + sRow) * Kin + kt + sCol];
            uint4 w1 = *(const uint4*)&Wt[(size_t)(col0 + sRow) * Kin + kt + sCol + 8];
            *(uint4*)&As[sRow][sCol]     = a0;
            *(uint4*)&As[sRow][sCol + 8] = a1;
            *(uint4*)&Ws[sRow][sCol]     = w0;
            *(uint4*)&Ws[sRow][sCol + 8] = w1;
        }
        __syncthreads();
        bf16x8 af[4], bf[4];
        const int k0 = (l >> 4) * 8;
        const int lr = l & 15;
#pragma unroll
        for (int m = 0; m < 4; m++)
            af[m] = *(const bf16x8*)&As[wr * 64 + m * 16 + lr][k0];
#pragma unroll
        for (int n = 0; n < 4; n++)
            bf[n] = *(const bf16x8*)&Ws[wc * 64 + n * 16 + lr][k0];
#pragma unroll
        for (int m = 0; m < 4; m++)
#pragma unroll
            for (int n = 0; n < 4; n++)
                acc[m][n] = __builtin_amdgcn_mfma_f32_16x16x32_bf16(af[m], bf[n], acc[m][n], 0, 0, 0);
    }

    float sse = 0.f;
#pragma unroll
    for (int m = 0; m < 4; m++)
#pragma unroll
        for (int n = 0; n < 4; n++) {
            const int rbase = row0 + wr * 64 + m * 16 + (l >> 4) * 4;
            const int c = col0 + wc * 64 + n * 16 + (l & 15);
            const float b = bias[c];
#pragma unroll
            for (int rr = 0; rr < 4; rr++) {
                float v = acc[m][n][rr] + b;
                if (FINAL) {
                    float d = v - x[(size_t)(rbase + rr) * N + c];
                    sse = fmaf(d, d, sse);
                    Cf[(size_t)(rbase + rr) * N + c] = v;
                } else {
                    if (RELU) v = fmaxf(v, 0.f);
                    Cb[(size_t)(rbase + rr) * N + c] = f2bf(v);
                }
            }
        }
    if (FINAL) {
        sse = wave_sum64(sse);
        if ((tid & 63) == 0) red[tid >> 6] = sse;
        __syncthreads();
        if (tid == 0) atomicAdd(sse_acc, red[0] + red[1] + red[2] + red[3]);
    }
}

// ---------------- finalize scalars ----------------
__global__ void finalize_kernel(const float* __restrict__ accv,
                                float* __restrict__ outs,
                                float inv_rec, float inv_cb) {
    if (threadIdx.x == 0) {
        outs[0] = accv[1] * inv_rec;     // recon_loss
        float cbl = accv[0] * inv_cb;
        outs[1] = cbl;                   // codebook_loss
        outs[2] = cbl;                   // commitment_loss (forward-equal)
    }
}

extern "C" void kernel_launch(void* const* d_in, const int* in_sizes, int n_in,
                              void* d_out, int out_size, void* d_ws, size_t ws_size,
                              hipStream_t stream) {
    const float* x     = (const float*)d_in[0];
    const float* W1    = (const float*)d_in[1];
    const float* b1    = (const float*)d_in[2];
    const float* W2    = (const float*)d_in[3];
    const float* b2    = (const float*)d_in[4];
    const float* W3    = (const float*)d_in[5];
    const float* b3    = (const float*)d_in[6];
    const float* gamma = (const float*)d_in[7];
    const float* beta  = (const float*)d_in[8];
    const float* cb    = (const float*)d_in[9];
    const float* D1    = (const float*)d_in[10];
    const float* c1    = (const float*)d_in[11];
    const float* D2    = (const float*)d_in[12];
    const float* c2    = (const float*)d_in[13];
    const float* D3    = (const float*)d_in[14];
    const float* c3    = (const float*)d_in[15];
    const int M = in_sizes[0] / IN_DIM;   // 65536

    float* out     = (float*)d_out;
    float* out_tok = out;                          // M*3
    float* out_rec = out + (size_t)M * 3;          // M*512
    float* out_sc  = out_rec + (size_t)M * IN_DIM; // 3 scalars

    const size_t fixedB  = (size_t)(16 + 2 * 3 * LCB * DC) * 4 + (size_t)172032 * 2;
    const size_t perRowB = (size_t)(3 * DC + 3 * 256 + 3 * 128) * 4;   // 5376
    int C = 4096;
    for (int cand = 65536; cand >= 4096; cand >>= 1)
        if (fixedB + (size_t)cand * perRowB <= ws_size) { C = cand; break; }

    float* ws    = (float*)d_ws;
    float* accv  = ws;                                     // 16
    float* cbn   = accv + 16;                              // 3*512*64
    float* cbnT  = cbn + 3 * LCB * DC;                     // 3*64*512
    unsigned short* D1t = (unsigned short*)(cbnT + 3 * DC * LCB);  // 128*64
    unsigned short* D2t = D1t + 128 * 64;                  // 256*128
    unsigned short* D3t = D2t + 256 * 128;                 // 512*256
    float* enc3  = (float*)(D3t + 512 * 256);              // 3*C*64 (enc, then q)
    float* H1    = enc3 + (size_t)3 * C * DC;              // 3*C*256
    float* H2    = H1 + (size_t)3 * C * 256;               // 3*C*128
    unsigned short* Aq  = (unsigned short*)H2;             // C*64 (aliases dead H2)
    unsigned short* H1b = Aq + (size_t)C * 64;             // C*128
    unsigned short* H2b = H1b + (size_t)C * 128;           // C*256

    cbnorm_kernel<<<dim3(3 * LCB / 4), dim3(256), 0, stream>>>(cb, cbn, cbnT, accv);
    wcvt_kernel<<<dim3(512), dim3(256), 0, stream>>>(D1, D2, D3, D1t, D2t, D3t);

    for (int off = 0; off < M; off += C) {
        const float* xc  = x + (size_t)off * IN_DIM;
        float*       rcc = out_rec + (size_t)off * IN_DIM;

        gemm_kernel<1><<<dim3(C / 256, 2, 3), dim3(512), 0, stream>>>(
            xc, W1, b1, H1, 512, 256,
            0, (size_t)512 * 256, 256, (size_t)C * 256);
        gemm_kernel<1><<<dim3(C / 256, 1, 3), dim3(512), 0, stream>>>(
            H1, W2, b2, H2, 256, 128,
            (size_t)C * 256, (size_t)256 * 128, 128, (size_t)C * 128);
        gemm_ln_kernel<<<dim3(C / 128, 3), dim3(256), 0, stream>>>(
            H2, W3, b3, gamma, beta, enc3, 128,
            (size_t)C * 128, (size_t)128 * 64, 64, (size_t)C * DC);
        quant_kernel<<<dim3(C / 128, 3), dim3(256), 0, stream>>>(
            enc3, cbnT, cbn, out_tok, accv + 0, off,
            (size_t)C * DC, (size_t)DC * LCB, (size_t)LCB * DC);

        avgq_kernel<<<dim3((C * 16 + 255) / 256), dim3(256), 0, stream>>>(
            enc3, Aq, C * 16, (size_t)C * DC);
        mfma_dec_kernel<1, 0><<<dim3(C / 128, 1), dim3(256), 0, stream>>>(
            Aq, D1t, c1, H1b, nullptr, nullptr, nullptr, 64, 128);
        mfma_dec_kernel<1, 0><<<dim3(C / 128, 2), dim3(256), 0, stream>>>(
            H1b, D2t, c2, H2b, nullptr, nullptr, nullptr, 128, 256);
        mfma_dec_kernel<0, 1><<<dim3(C / 128, 4), dim3(256), 0, stream>>>(
            H2b, D3t, c3, nullptr, rcc, xc, accv + 1, 256, 512);
    }

    finalize_kernel<<<dim3(1), dim3(64), 0, stream>>>(
        accv, out_sc, 1.f / ((float)M * IN_DIM), 1.f / ((float)M * DC));
}

// Round 11
// 1233.534 us; speedup vs baseline: 1.3951x; 1.0595x over previous
//
#include <hip/hip_runtime.h>
#include <hip/hip_bf16.h>

using f4 = float4;
typedef __attribute__((ext_vector_type(8))) short bf16x8;
typedef __attribute__((ext_vector_type(4))) float f32x4;

constexpr int IN_DIM = 512;
constexpr int DC     = 64;
constexpr int LCB    = 512;

__device__ __forceinline__ float wave_sum64(float v) {
#pragma unroll
    for (int m = 1; m < 64; m <<= 1) v += __shfl_xor(v, m, 64);
    return v;
}

__device__ __forceinline__ unsigned short f2bf(float v) {
    __hip_bfloat16 h = __float2bfloat16(v);
    return *(unsigned short*)&h;
}

// ---------------- codebook L2-normalize (also builds transposed copy) -------
__global__ void cbnorm_kernel(const float* __restrict__ cb, float* __restrict__ cbn,
                              float* __restrict__ cbnT, float* __restrict__ accv) {
    int row  = blockIdx.x * 4 + (threadIdx.x >> 6);  // 0..1535 (k*512 + l)
    int lane = threadIdx.x & 63;
    float v  = cb[(size_t)row * DC + lane];
    float ss = wave_sum64(v * v);
    float n  = sqrtf(ss);
    float o  = v / fmaxf(n, 1e-12f);
    cbn[(size_t)row * DC + lane] = o;
    int k = row >> 9, l = row & 511;
    cbnT[((size_t)k * DC + lane) * LCB + l] = o;
    if (blockIdx.x == 0 && threadIdx.x < 16) accv[threadIdx.x] = 0.f;
}

// ---------------- decoder weights -> transposed bf16 ------------------------
__global__ void wcvt_kernel(const float* __restrict__ D1, const float* __restrict__ D2,
                            const float* __restrict__ D3, unsigned short* __restrict__ D1t,
                            unsigned short* __restrict__ D2t, unsigned short* __restrict__ D3t) {
    int i = blockIdx.x * 256 + threadIdx.x;
    if (i < 128 * 64)  { int n = i >> 6, k = i & 63;  D1t[i] = f2bf(D1[(size_t)k * 128 + n]); }
    if (i < 256 * 128) { int n = i >> 7, k = i & 127; D2t[i] = f2bf(D2[(size_t)k * 256 + n]); }
    if (i < 512 * 256) { int n = i >> 8, k = i & 255; D3t[i] = f2bf(D3[(size_t)k * 512 + n]); }
}

// ---------------- avg_q (f32 q planes) -> bf16 ------------------------------
__global__ void avgq_kernel(const float* __restrict__ q3, unsigned short* __restrict__ Aq,
                            int n4, size_t planeStride) {
    int i = blockIdx.x * blockDim.x + threadIdx.x;
    if (i >= n4) return;
    f4 a = *(const f4*)&q3[(size_t)i * 4];
    f4 b = *(const f4*)&q3[planeStride + (size_t)i * 4];
    f4 c = *(const f4*)&q3[2 * planeStride + (size_t)i * 4];
    const float s = 1.f / 3.f;
    unsigned int lo = f2bf((a.x + b.x + c.x) * s) | ((unsigned int)f2bf((a.y + b.y + c.y) * s) << 16);
    unsigned int hi = f2bf((a.z + b.z + c.z) * s) | ((unsigned int)f2bf((a.w + b.w + c.w) * s) << 16);
    uint2 o; o.x = lo; o.y = hi;
    *(uint2*)&Aq[(size_t)i * 4] = o;
}

// ---------------- fp32 GEMM (r8-exact, proven 590us): C = act(A@W + bias) ---
// 128x128x32 tile, 256 thr, 8x8/thread. Empirical local optimum: r5 prefetch
// (L3 thrash), r6 conflict-free LDS (neutral), r8 pk-fma (neutral), r9 16x8
// (VGPR spill), r10 512-thr (TLP loss) all <= this. ~56% of fp32 peak =
// issue-busy(76%) x FMA-density(94%) x sustained-clock(~2.0/2.4 GHz).
// FMA chain order p=0..Kin sequential -> bit-identical enc (token anchor).
template <int RELU>
__global__ __launch_bounds__(256, 4)
void gemm_kernel(const float* __restrict__ A, const float* __restrict__ W,
                 const float* __restrict__ bias, float* __restrict__ C,
                 int Kin, int N,
                 size_t aK, size_t wK, size_t bK, size_t cK) {
    constexpr int BM = 128, BN = 128, BK = 32;
    __shared__ alignas(16) float As[BK][BM + 4];
    __shared__ alignas(16) float Ws[BK][BN + 4];
    const int z = blockIdx.z;
    A += (size_t)z * aK;  W += (size_t)z * wK;
    bias += (size_t)z * bK;  C += (size_t)z * cK;
    const int tid = threadIdx.x;
    const int tx = tid & 15, ty = tid >> 4;
    const int row0 = blockIdx.x * BM, col0 = blockIdx.y * BN;

    float acc[8][8];
#pragma unroll
    for (int i = 0; i < 8; i++)
#pragma unroll
        for (int j = 0; j < 8; j++) acc[i][j] = 0.f;

    const int aRow = tid >> 3;
    const int aCol = (tid & 7) * 4;
    const int wRow = tid >> 5;
    const int wCol = (tid & 31) * 4;

    for (int kk = 0; kk < Kin; kk += BK) {
#pragma unroll
        for (int it = 0; it < 4; it++) {
            f4 v = *(const f4*)&A[(size_t)(row0 + aRow + it * 32) * Kin + kk + aCol];
            As[aCol + 0][aRow + it * 32] = v.x;
            As[aCol + 1][aRow + it * 32] = v.y;
            As[aCol + 2][aRow + it * 32] = v.z;
            As[aCol + 3][aRow + it * 32] = v.w;
        }
#pragma unroll
        for (int it = 0; it < 4; it++) {
            f4 v = *(const f4*)&W[(size_t)(kk + wRow + it * 8) * N + col0 + wCol];
            *(f4*)&Ws[wRow + it * 8][wCol] = v;
        }
        __syncthreads();
#pragma unroll
        for (int p = 0; p < BK; p++) {
            f4 a0 = *(const f4*)&As[p][ty * 8];
            f4 a1 = *(const f4*)&As[p][ty * 8 + 4];
            f4 w0 = *(const f4*)&Ws[p][tx * 8];
            f4 w1 = *(const f4*)&Ws[p][tx * 8 + 4];
            float av[8] = {a0.x, a0.y, a0.z, a0.w, a1.x, a1.y, a1.z, a1.w};
            float wv[8] = {w0.x, w0.y, w0.z, w0.w, w1.x, w1.y, w1.z, w1.w};
#pragma unroll
            for (int i = 0; i < 8; i++)
#pragma unroll
                for (int j = 0; j < 8; j++)
                    acc[i][j] = fmaf(av[i], wv[j], acc[i][j]);
        }
        __syncthreads();
    }

#pragma unroll
    for (int i = 0; i < 8; i++) {
        const size_t r = (size_t)row0 + ty * 8 + i;
        float vrow[8];
#pragma unroll
        for (int j = 0; j < 8; j++) {
            float v = acc[i][j] + bias[col0 + tx * 8 + j];
            if (RELU) v = fmaxf(v, 0.f);
            vrow[j] = v;
        }
        *(f4*)&C[r * N + col0 + tx * 8]     = *(f4*)&vrow[0];
        *(f4*)&C[r * N + col0 + tx * 8 + 4] = *(f4*)&vrow[4];
    }
}

// ---------------- GEMM3 + LayerNorm epilogue: enc = LN(A@W3 + b3) -----------
__global__ __launch_bounds__(256, 4)
void gemm_ln_kernel(const float* __restrict__ A, const float* __restrict__ W,
                    const float* __restrict__ bias, const float* __restrict__ gamma,
                    const float* __restrict__ beta, float* __restrict__ enc, int Kin,
                    size_t aK, size_t wK, size_t bK, size_t eK) {
    constexpr int BM = 128, BK = 32;
    __shared__ alignas(16) float As[BK][BM + 4];
    __shared__ alignas(16) float Ws[BK][DC + 4];
    const int z = blockIdx.y;
    A += (size_t)z * aK;  W += (size_t)z * wK;
    bias += (size_t)z * bK;  enc += (size_t)z * eK;
    const int tid = threadIdx.x;
    const int tx = tid & 7, ty = tid >> 3;
    const int row0 = blockIdx.x * BM;

    float acc[4][8];
#pragma unroll
    for (int i = 0; i < 4; i++)
#pragma unroll
        for (int j = 0; j < 8; j++) acc[i][j] = 0.f;

    const int aRow = tid >> 3;
    const int aCol = (tid & 7) * 4;
    const int wRow = tid >> 4;
    const int wCol = (tid & 15) * 4;

    for (int kk = 0; kk < Kin; kk += BK) {
#pragma unroll
        for (int it = 0; it < 4; it++) {
            f4 v = *(const f4*)&A[(size_t)(row0 + aRow + it * 32) * Kin + kk + aCol];
            As[aCol + 0][aRow + it * 32] = v.x;
            As[aCol + 1][aRow + it * 32] = v.y;
            As[aCol + 2][aRow + it * 32] = v.z;
            As[aCol + 3][aRow + it * 32] = v.w;
        }
#pragma unroll
        for (int it = 0; it < 2; it++) {
            f4 v = *(const f4*)&W[(size_t)(kk + wRow + it * 16) * DC + wCol];
            *(f4*)&Ws[wRow + it * 16][wCol] = v;
        }
        __syncthreads();
#pragma unroll
        for (int p = 0; p < BK; p++) {
            f4 a  = *(const f4*)&As[p][ty * 4];
            f4 w0 = *(const f4*)&Ws[p][tx * 8];
            f4 w1 = *(const f4*)&Ws[p][tx * 8 + 4];
            float av[4] = {a.x, a.y, a.z, a.w};
            float wv[8] = {w0.x, w0.y, w0.z, w0.w, w1.x, w1.y, w1.z, w1.w};
#pragma unroll
            for (int i = 0; i < 4; i++)
#pragma unroll
                for (int j = 0; j < 8; j++)
                    acc[i][j] = fmaf(av[i], wv[j], acc[i][j]);
        }
        __syncthreads();
    }

#pragma unroll
    for (int i = 0; i < 4; i++) {
        float vrow[8];
#pragma unroll
        for (int j = 0; j < 8; j++) vrow[j] = acc[i][j] + bias[tx * 8 + j];
        float s = 0.f;
#pragma unroll
        for (int j = 0; j < 8; j++) s += vrow[j];
#pragma unroll
        for (int m = 1; m < 8; m <<= 1) s += __shfl_xor(s, m, 8);
        float mu = s * (1.f / 64.f);
        float d2 = 0.f;
#pragma unroll
        for (int j = 0; j < 8; j++) { float d = vrow[j] - mu; d2 = fmaf(d, d, d2); }
#pragma unroll
        for (int m = 1; m < 8; m <<= 1) d2 += __shfl_xor(d2, m, 8);
        float rs = 1.f / sqrtf(d2 * (1.f / 64.f) + 1e-5f);
#pragma unroll
        for (int j = 0; j < 8; j++) {
            int c = tx * 8 + j;
            vrow[j] = (vrow[j] - mu) * rs * gamma[c] + beta[c];
        }
        const size_t r = (size_t)row0 + ty * 4 + i;
        *(f4*)&enc[r * DC + tx * 8]     = *(f4*)&vrow[0];
        *(f4*)&enc[r * DC + tx * 8 + 4] = *(f4*)&vrow[4];
    }
}

// ---------------- quantize (f64 scores, round-6 proven) ---------------------
__global__ __launch_bounds__(256, 2)
void quant_kernel(float* __restrict__ enc, const float* __restrict__ cbT,
                  const float* __restrict__ cbn, float* __restrict__ out_tok,
                  float* __restrict__ sse_acc, int row_off_glob,
                  size_t eK, size_t cbTK, size_t cbnK) {
    constexpr int BM = 128;
    __shared__ alignas(16) float Es[DC][BM + 4];
    __shared__ alignas(16) float Cs[DC][64 + 4];
    __shared__ float red[4];
    const int k = blockIdx.y;
    enc += (size_t)k * eK;
    cbT += (size_t)k * cbTK;
    cbn += (size_t)k * cbnK;
    const int tid = threadIdx.x;
    const int tx = tid & 7, ty = tid >> 3;
    const int row0 = blockIdx.x * BM;

    {   // load enc tile transposed
        const int r  = tid >> 1;
        const int c0 = (tid & 1) * 32;
#pragma unroll
        for (int i = 0; i < 8; i++) {
            f4 v = *(const f4*)&enc[(size_t)(row0 + r) * DC + c0 + i * 4];
            Es[c0 + i * 4 + 0][r] = v.x;
            Es[c0 + i * 4 + 1][r] = v.y;
            Es[c0 + i * 4 + 2][r] = v.z;
            Es[c0 + i * 4 + 3][r] = v.w;
        }
    }

    double mx[4]; int mi[4];
#pragma unroll
    for (int i = 0; i < 4; i++) { mx[i] = -1.0e300; mi[i] = 0; }

    for (int lc = 0; lc < LCB; lc += 64) {
        __syncthreads();
        {
            const int p  = tid >> 2;
            const int c0 = (tid & 3) * 16;
#pragma unroll
            for (int i = 0; i < 4; i++)
                *(f4*)&Cs[p][c0 + i * 4] =
                    *(const f4*)&cbT[(size_t)p * LCB + lc + c0 + i * 4];
        }
        __syncthreads();
        double sc[4][8];
#pragma unroll
        for (int i = 0; i < 4; i++)
#pragma unroll
            for (int j = 0; j < 8; j++) sc[i][j] = 0.0;
#pragma unroll
        for (int p = 0; p < DC; p++) {
            f4 a  = *(const f4*)&Es[p][ty * 4];
            f4 w0 = *(const f4*)&Cs[p][tx * 8];
            f4 w1 = *(const f4*)&Cs[p][tx * 8 + 4];
            double av[4] = {a.x, a.y, a.z, a.w};
            double wv[8] = {w0.x, w0.y, w0.z, w0.w, w1.x, w1.y, w1.z, w1.w};
#pragma unroll
            for (int i = 0; i < 4; i++)
#pragma unroll
                for (int j = 0; j < 8; j++)
                    sc[i][j] = fma(av[i], wv[j], sc[i][j]);
        }
#pragma unroll
        for (int i = 0; i < 4; i++)
#pragma unroll
            for (int j = 0; j < 8; j++) {
                int l = lc + tx * 8 + j;
                if (sc[i][j] > mx[i]) { mx[i] = sc[i][j]; mi[i] = l; }
            }
    }

#pragma unroll
    for (int m = 1; m < 8; m <<= 1)
#pragma unroll
        for (int i = 0; i < 4; i++) {
            double omx = __shfl_xor(mx[i], m, 8);
            int    omi = __shfl_xor(mi[i], m, 8);
            if (omx > mx[i] || (omx == mx[i] && omi < mi[i])) { mx[i] = omx; mi[i] = omi; }
        }

    float sse = 0.f;
#pragma unroll
    for (int i = 0; i < 4; i++) {
        const int rl = ty * 4 + i;
        const size_t r = (size_t)row0 + rl;
        f4 q0 = *(const f4*)&cbn[(size_t)mi[i] * DC + tx * 8];
        f4 q1 = *(const f4*)&cbn[(size_t)mi[i] * DC + tx * 8 + 4];
        float qv[8] = {q0.x, q0.y, q0.z, q0.w, q1.x, q1.y, q1.z, q1.w};
#pragma unroll
        for (int j = 0; j < 8; j++) {
            float e = Es[tx * 8 + j][rl];
            float d = e - qv[j];
            sse = fmaf(d, d, sse);
        }
        *(f4*)&enc[r * DC + tx * 8]     = q0;
        *(f4*)&enc[r * DC + tx * 8 + 4] = q1;
        if (tx == 0) out_tok[(size_t)(row_off_glob + r) * 3 + k] = (float)mi[i];
    }
    sse = wave_sum64(sse);
    if ((tid & 63) == 0) red[tid >> 6] = sse;
    __syncthreads();
    if (tid == 0) atomicAdd(sse_acc, red[0] + red[1] + red[2] + red[3]);
}

// ---------------- bf16 MFMA GEMM for decoder (r7 proven) --------------------
template <int RELU, int FINAL>
__global__ __launch_bounds__(256, 2)
void mfma_dec_kernel(const unsigned short* __restrict__ A,
                     const unsigned short* __restrict__ Wt,
                     const float* __restrict__ bias,
                     unsigned short* __restrict__ Cb, float* __restrict__ Cf,
                     const float* __restrict__ x, float* __restrict__ sse_acc,
                     int Kin, int N) {
    constexpr int BM = 128, BN = 128, BK = 32;
    __shared__ alignas(16) unsigned short As[BM][BK + 8];
    __shared__ alignas(16) unsigned short Ws[BN][BK + 8];
    __shared__ float red[4];
    const int tid = threadIdx.x;
    const int l = tid & 63, wave = tid >> 6;
    const int wr = wave >> 1, wc = wave & 1;
    const int row0 = blockIdx.x * BM, col0 = blockIdx.y * BN;

    f32x4 acc[4][4];
#pragma unroll
    for (int m = 0; m < 4; m++)
#pragma unroll
        for (int n = 0; n < 4; n++) acc[m][n] = (f32x4){0.f, 0.f, 0.f, 0.f};

    const int sRow = tid >> 1;
    const int sCol = (tid & 1) * 16;

    for (int kt = 0; kt < Kin; kt += BK) {
        __syncthreads();
        {
            uint4 a0 = *(const uint4*)&A[(size_t)(row0 + sRow) * Kin + kt + sCol];
            uint4 a1 = *(const uint4*)&A[(size_t)(row0 + sRow) * Kin + kt + sCol + 8];
            uint4 w0 = *(const uint4*)&Wt[(size_t)(col0 + sRow) * Kin + kt + sCol];
            uint4 w1 = *(const uint4*)&Wt[(size_t)(col0 + sRow) * Kin + kt + sCol + 8];
            *(uint4*)&As[sRow][sCol]     = a0;
            *(uint4*)&As[sRow][sCol + 8] = a1;
            *(uint4*)&Ws[sRow][sCol]     = w0;
            *(uint4*)&Ws[sRow][sCol + 8] = w1;
        }
        __syncthreads();
        bf16x8 af[4], bf[4];
        const int k0 = (l >> 4) * 8;
        const int lr = l & 15;
#pragma unroll
        for (int m = 0; m < 4; m++)
            af[m] = *(const bf16x8*)&As[wr * 64 + m * 16 + lr][k0];
#pragma unroll
        for (int n = 0; n < 4; n++)
            bf[n] = *(const bf16x8*)&Ws[wc * 64 + n * 16 + lr][k0];
#pragma unroll
        for (int m = 0; m < 4; m++)
#pragma unroll
            for (int n = 0; n < 4; n++)
                acc[m][n] = __builtin_amdgcn_mfma_f32_16x16x32_bf16(af[m], bf[n], acc[m][n], 0, 0, 0);
    }

    float sse = 0.f;
#pragma unroll
    for (int m = 0; m < 4; m++)
#pragma unroll
        for (int n = 0; n < 4; n++) {
            const int rbase = row0 + wr * 64 + m * 16 + (l >> 4) * 4;
            const int c = col0 + wc * 64 + n * 16 + (l & 15);
            const float b = bias[c];
#pragma unroll
            for (int rr = 0; rr < 4; rr++) {
                float v = acc[m][n][rr] + b;
                if (FINAL) {
                    float d = v - x[(size_t)(rbase + rr) * N + c];
                    sse = fmaf(d, d, sse);
                    Cf[(size_t)(rbase + rr) * N + c] = v;
                } else {
                    if (RELU) v = fmaxf(v, 0.f);
                    Cb[(size_t)(rbase + rr) * N + c] = f2bf(v);
                }
            }
        }
    if (FINAL) {
        sse = wave_sum64(sse);
        if ((tid & 63) == 0) red[tid >> 6] = sse;
        __syncthreads();
        if (tid == 0) atomicAdd(sse_acc, red[0] + red[1] + red[2] + red[3]);
    }
}

// ---------------- finalize scalars ----------------
__global__ void finalize_kernel(const float* __restrict__ accv,
                                float* __restrict__ outs,
                                float inv_rec, float inv_cb) {
    if (threadIdx.x == 0) {
        outs[0] = accv[1] * inv_rec;     // recon_loss
        float cbl = accv[0] * inv_cb;
        outs[1] = cbl;                   // codebook_loss
        outs[2] = cbl;                   // commitment_loss (forward-equal)
    }
}

extern "C" void kernel_launch(void* const* d_in, const int* in_sizes, int n_in,
                              void* d_out, int out_size, void* d_ws, size_t ws_size,
                              hipStream_t stream) {
    const float* x     = (const float*)d_in[0];
    const float* W1    = (const float*)d_in[1];
    const float* b1    = (const float*)d_in[2];
    const float* W2    = (const float*)d_in[3];
    const float* b2    = (const float*)d_in[4];
    const float* W3    = (const float*)d_in[5];
    const float* b3    = (const float*)d_in[6];
    const float* gamma = (const float*)d_in[7];
    const float* beta  = (const float*)d_in[8];
    const float* cb    = (const float*)d_in[9];
    const float* D1    = (const float*)d_in[10];
    const float* c1    = (const float*)d_in[11];
    const float* D2    = (const float*)d_in[12];
    const float* c2    = (const float*)d_in[13];
    const float* D3    = (const float*)d_in[14];
    const float* c3    = (const float*)d_in[15];
    const int M = in_sizes[0] / IN_DIM;   // 65536

    float* out     = (float*)d_out;
    float* out_tok = out;                          // M*3
    float* out_rec = out + (size_t)M * 3;          // M*512
    float* out_sc  = out_rec + (size_t)M * IN_DIM; // 3 scalars

    const size_t fixedB  = (size_t)(16 + 2 * 3 * LCB * DC) * 4 + (size_t)172032 * 2;
    const size_t perRowB = (size_t)(3 * DC + 3 * 256 + 3 * 128) * 4;   // 5376
    int C = 4096;
    for (int cand = 65536; cand >= 4096; cand >>= 1)
        if (fixedB + (size_t)cand * perRowB <= ws_size) { C = cand; break; }

    float* ws    = (float*)d_ws;
    float* accv  = ws;                                     // 16
    float* cbn   = accv + 16;                              // 3*512*64
    float* cbnT  = cbn + 3 * LCB * DC;                     // 3*64*512
    unsigned short* D1t = (unsigned short*)(cbnT + 3 * DC * LCB);  // 128*64
    unsigned short* D2t = D1t + 128 * 64;                  // 256*128
    unsigned short* D3t = D2t + 256 * 128;                 // 512*256
    float* enc3  = (float*)(D3t + 512 * 256);              // 3*C*64 (enc, then q)
    float* H1    = enc3 + (size_t)3 * C * DC;              // 3*C*256
    float* H2    = H1 + (size_t)3 * C * 256;               // 3*C*128
    unsigned short* Aq  = (unsigned short*)H2;             // C*64 (aliases dead H2)
    unsigned short* H1b = Aq + (size_t)C * 64;             // C*128
    unsigned short* H2b = H1b + (size_t)C * 128;           // C*256

    cbnorm_kernel<<<dim3(3 * LCB / 4), dim3(256), 0, stream>>>(cb, cbn, cbnT, accv);
    wcvt_kernel<<<dim3(512), dim3(256), 0, stream>>>(D1, D2, D3, D1t, D2t, D3t);

    for (int off = 0; off < M; off += C) {
        const float* xc  = x + (size_t)off * IN_DIM;
        float*       rcc = out_rec + (size_t)off * IN_DIM;

        gemm_kernel<1><<<dim3(C / 128, 2, 3), dim3(256), 0, stream>>>(
            xc, W1, b1, H1, 512, 256,
            0, (size_t)512 * 256, 256, (size_t)C * 256);
        gemm_kernel<1><<<dim3(C / 128, 1, 3), dim3(256), 0, stream>>>(
            H1, W2, b2, H2, 256, 128,
            (size_t)C * 256, (size_t)256 * 128, 128, (size_t)C * 128);
        gemm_ln_kernel<<<dim3(C / 128, 3), dim3(256), 0, stream>>>(
            H2, W3, b3, gamma, beta, enc3, 128,
            (size_t)C * 128, (size_t)128 * 64, 64, (size_t)C * DC);
        quant_kernel<<<dim3(C / 128, 3), dim3(256), 0, stream>>>(
            enc3, cbnT, cbn, out_tok, accv + 0, off,
            (size_t)C * DC, (size_t)DC * LCB, (size_t)LCB * DC);

        avgq_kernel<<<dim3((C * 16 + 255) / 256), dim3(256), 0, stream>>>(
            enc3, Aq, C * 16, (size_t)C * DC);
        mfma_dec_kernel<1, 0><<<dim3(C / 128, 1), dim3(256), 0, stream>>>(
            Aq, D1t, c1, H1b, nullptr, nullptr, nullptr, 64, 128);
        mfma_dec_kernel<1, 0><<<dim3(C / 128, 2), dim3(256), 0, stream>>>(
            H1b, D2t, c2, H2b, nullptr, nullptr, nullptr, 128, 256);
        mfma_dec_kernel<0, 1><<<dim3(C / 128, 4), dim3(256), 0, stream>>>(
            H2b, D3t, c3, nullptr, rcc, xc, accv + 1, 256, 512);
    }

    finalize_kernel<<<dim3(1), dim3(64), 0, stream>>>(
        accv, out_sc, 1.f / ((float)M * IN_DIM), 1.f / ((float)M * DC));
}